// Round 13
// baseline (29.185 us; speedup 1.0000x reference)
//
#include <hip/hip_runtime.h>
#include <stdint.h>

typedef _Float16 f16;
typedef f16   f16x2 __attribute__((ext_vector_type(2)));
typedef f16   f16x8 __attribute__((ext_vector_type(8)));
typedef float f32x4 __attribute__((ext_vector_type(4)));

static constexpr int M_ = 64;
static constexpr int K_ = 4096;
static constexpr int N_ = 14336;

// x fp32 [64][4096] -> f16, tiled into MFMA-fragment order:
// f16x8-slot ((kg*4+mt)*64 + h*16 + l16) holds x[mt*16+l16][(kg*4+h)*8 .. +8)
// (kg = global k-step of 32). One BK=128 chunk (4 ksteps) = 16 KB contiguous.
__global__ void xconv_kernel(const float* __restrict__ x, uint4* __restrict__ xt) {
    int t = blockIdx.x * blockDim.x + threadIdx.x;      // 32768 threads
    int row = t >> 9, kb = t & 511;
    int kg = kb >> 2, h = kb & 3, mt = row >> 4, l16 = row & 15;
    int dst = (kg * 4 + mt) * 64 + h * 16 + l16;
    const float4* p = reinterpret_cast<const float4*>(x) + 2 * (size_t)t;   // coalesced read
    float4 a = p[0], b = p[1];
    union { f16x8 h8; uint4 v; } z;
    z.h8[0] = (f16)a.x; z.h8[1] = (f16)a.y; z.h8[2] = (f16)a.z; z.h8[3] = (f16)a.w;
    z.h8[4] = (f16)b.x; z.h8[5] = (f16)b.y; z.h8[6] = (f16)b.z; z.h8[7] = (f16)b.w;
    xt[dst] = z.v;
}

__device__ __forceinline__ void gl16(const void* g, void* l) {
    __builtin_amdgcn_global_load_lds(
        (const __attribute__((address_space(1))) void*)g,
        (__attribute__((address_space(3))) void*)l, 16, 0, 0);
}
__device__ __forceinline__ void gl4(const void* g, void* l) {
    __builtin_amdgcn_global_load_lds(
        (const __attribute__((address_space(1))) void*)g,
        (__attribute__((address_space(3))) void*)l, 4, 0, 0);
}

// nibble->f16 dequant: 0x6400|n = 1024+n exact; pk_add(-1032) -> n-8 exact; pk_mul(s).
// packed dword nibble p -> frag slot 2p, nibble p+4 -> slot 2p+1 (folds pack-perm).
__device__ __forceinline__ f16x8 dequant(uint u, f16x2 sc) {
    const f16 m = (f16)(-1032.0f);
    const f16x2 mc = {m, m};
    union { f16x2 h2; uint uu; } um;
    union { f16x2 h2[4]; f16x8 v; } ob;
    #pragma unroll
    for (int p = 0; p < 4; ++p) {
        um.uu = 0x64006400u | ((u >> (4 * p)) & 0x000F000Fu);
        ob.h2[p] = (um.h2 + mc) * sc;
    }
    return ob.v;
}

// grid=448 (BN=32), block=512=8 waves, 32 iters of BK=128 (= 1 scale group).
// m97/m201 pattern: compute reads ONLY LDS; globals enter ONLY via cooperative
// global_load_lds bursts into a 3-buffer pipeline (A 16KB + B 2KB + S 256B per
// buffer, 56KB total -> 2 blocks/CU). Iter top: s_waitcnt vmcnt(4) (stage(it+1)
// stays in flight -- NEVER 0 mid-loop) + raw s_barrier. Stage(it+2) issues
// after compute (2-iter latency window). Wave (kq,mhalf): kstep kq, m-rows
// mhalf*32..+32, all 32 n-cols -> no dequant duplication, A read 1x/iter.
// Epilogue: kq-reduce via LDS exchange.
template<bool PRE>
__global__ __launch_bounds__(512, 4)
void gemm_kernel(const float* __restrict__ xf, const f16x8* __restrict__ xt8,
                 const uint* __restrict__ bpk, const float* __restrict__ s,
                 float* __restrict__ out)
{
    __shared__ __align__(16) uint lbs[14016];           // 3 x 4672 dwords = 56064 B
    const int tid  = threadIdx.x;
    const int lane = tid & 63;
    const int w    = tid >> 6;
    const int h    = lane >> 4;
    const int l16  = lane & 15;
    const int kq   = w >> 1;                            // k-step within iter 0..3
    const int mhalf= w & 1;                             // m-half 0..1
    const int n0   = blockIdx.x * 32;

    const char* xtb  = (const char*)xt8;
    const char* bpkb = (const char*)bpk;
    const char* sb   = (const char*)s;

    // stage iter j into buffer j%3 (4 vmem ops per thread-wave, uniform count)
    auto stage = [&](int j) {
        const int bo = (j % 3) * 18688;                 // byte offset of buffer
        if constexpr (PRE) {
            gl16(xtb + (size_t)j * 16384 + (size_t)tid * 16,
                 (char*)lbs + bo + w * 1024);
            gl16(xtb + (size_t)j * 16384 + 8192 + (size_t)tid * 16,
                 (char*)lbs + bo + 8192 + w * 1024);
            gl4(bpkb + ((size_t)(n0 + (tid >> 4)) * 512 + j * 16 + (tid & 15)) * 4,
                (char*)lbs + bo + 16384 + w * 256);
            gl4(sb + ((size_t)j * N_ + n0 + (lane < 32 ? lane : 31)) * 4,
                (char*)lbs + bo + 18432);               // lanes>=32 write unused pad
        } else {
            const int bq = bo >> 2;
            #pragma unroll
            for (int q = 0; q < 2; ++q) {
                int si = q * 512 + tid;
                int kgl = si >> 8, rem = si & 255;
                int mt = rem >> 6, sub = rem & 63, hh = sub >> 4, ll = sub & 15;
                const float* xp = xf + (size_t)(mt * 16 + ll) * K_ + (size_t)((j * 4 + kgl) * 4 + hh) * 8;
                float4 f0 = *reinterpret_cast<const float4*>(xp);
                float4 f1 = *reinterpret_cast<const float4*>(xp + 4);
                f16x8 av;
                av[0] = (f16)f0.x; av[1] = (f16)f0.y; av[2] = (f16)f0.z; av[3] = (f16)f0.w;
                av[4] = (f16)f1.x; av[5] = (f16)f1.y; av[6] = (f16)f1.z; av[7] = (f16)f1.w;
                *reinterpret_cast<f16x8*>((char*)lbs + bo + si * 16) = av;
            }
            lbs[bq + 4096 + tid] = bpk[(size_t)(n0 + (tid >> 4)) * 512 + j * 16 + (tid & 15)];
            if (tid < 32)
                reinterpret_cast<float*>((char*)lbs + bo + 18432)[tid] = s[(size_t)j * N_ + n0 + tid];
        }
    };

    f32x4 c00 = {0,0,0,0}, c01 = {0,0,0,0}, c10 = {0,0,0,0}, c11 = {0,0,0,0};

    stage(0);
    stage(1);

    #pragma unroll
    for (int it = 0; it < 32; ++it) {
        if constexpr (PRE) {
            if (it < 31) { asm volatile("s_waitcnt vmcnt(4)" ::: "memory"); }
            else         { asm volatile("s_waitcnt vmcnt(0)" ::: "memory"); }
        } else {
            asm volatile("s_waitcnt vmcnt(0) lgkmcnt(0)" ::: "memory");
        }
        __builtin_amdgcn_s_barrier();

        // ---- compute iter it from buffer it%3 (LDS only) ----
        const int bd = (it % 3) * 4672;                 // dword offset
        const float* Sf = reinterpret_cast<const float*>(lbs + bd + 4608);
        const float s0f = Sf[l16], s1f = Sf[16 + l16];  // broadcast reads
        const f16 s0h = (f16)s0f, s1h = (f16)s1f;
        const uint u0 = lbs[bd + 4096 + l16 * 16 + kq * 4 + h];
        const uint u1 = lbs[bd + 4096 + (16 + l16) * 16 + kq * 4 + h];
        const f16x8 b0 = dequant(u0, f16x2{s0h, s0h});
        const f16x8 b1 = dequant(u1, f16x2{s1h, s1h});
        const f16x8* Ap = reinterpret_cast<const f16x8*>(lbs + bd);
        const f16x8 a0 = Ap[(kq * 4 + mhalf * 2 + 0) * 64 + lane];  // contig 1KB: no conflict
        const f16x8 a1 = Ap[(kq * 4 + mhalf * 2 + 1) * 64 + lane];
        c00 = __builtin_amdgcn_mfma_f32_16x16x32_f16(a0, b0, c00, 0, 0, 0);
        c01 = __builtin_amdgcn_mfma_f32_16x16x32_f16(a0, b1, c01, 0, 0, 0);
        c10 = __builtin_amdgcn_mfma_f32_16x16x32_f16(a1, b0, c10, 0, 0, 0);
        c11 = __builtin_amdgcn_mfma_f32_16x16x32_f16(a1, b1, c11, 0, 0, 0);

        if (it < 30) stage(it + 2);                     // 2-iter latency window
    }

    // ---- epilogue: kq-reduce via LDS exchange ----
    __syncthreads();
    f32x4* red = reinterpret_cast<f32x4*>(lbs);         // 8 waves x 4 slots x 64 = 32KB
    red[(w * 4 + 0) * 64 + lane] = c00;                 // (mtl=0, nt=0)
    red[(w * 4 + 1) * 64 + lane] = c01;                 // (mtl=0, nt=1)
    red[(w * 4 + 2) * 64 + lane] = c10;                 // (mtl=1, nt=0)
    red[(w * 4 + 3) * 64 + lane] = c11;                 // (mtl=1, nt=1)
    __syncthreads();
    {   // wave w owns output slot: mt_o = w>>1 (0..3), nt_o = w&1
        const int mt_o = w >> 1, nt_o = w & 1;
        const int mh = mt_o >> 1, idx = (mt_o & 1) * 2 + nt_o;
        f32x4 v = red[((0 * 2 + mh) * 4 + idx) * 64 + lane];
        v += red[((1 * 2 + mh) * 4 + idx) * 64 + lane];
        v += red[((2 * 2 + mh) * 4 + idx) * 64 + lane];
        v += red[((3 * 2 + mh) * 4 + idx) * 64 + lane];
        // C/D: row = mt_o*16 + h*4 + q, col = n0 + nt_o*16 + l16
        #pragma unroll
        for (int q = 0; q < 4; ++q)
            out[(size_t)(mt_o * 16 + h * 4 + q) * N_ + (n0 + nt_o * 16 + l16)] = v[q];
    }
}

extern "C" void kernel_launch(void* const* d_in, const int* in_sizes, int n_in,
                              void* d_out, int out_size, void* d_ws, size_t ws_size,
                              hipStream_t stream) {
    const float* x   = (const float*)d_in[0];
    const uint*  bpk = (const uint*)d_in[1];
    const float* s   = (const float*)d_in[2];
    float*       out = (float*)d_out;

    if (ws_size >= (size_t)(M_ * K_ * 2)) {
        xconv_kernel<<<128, 256, 0, stream>>>(x, (uint4*)d_ws);
        gemm_kernel<true><<<448, 512, 0, stream>>>(x, (const f16x8*)d_ws, bpk, s, out);
    } else {
        gemm_kernel<false><<<448, 512, 0, stream>>>(x, nullptr, bpk, s, out);
    }
}